// Round 8
// baseline (175.347 us; speedup 1.0000x reference)
//
#include <hip/hip_runtime.h>

// ---- types ----
typedef _Float16 halfx8 __attribute__((ext_vector_type(8)));
typedef float floatx4 __attribute__((ext_vector_type(4)));
typedef float floatx2 __attribute__((ext_vector_type(2)));

// problem dims
#define PM 16384
#define PD 768
#define PA 51
#define NBLK 1024u

// Math identity (verified): logits = x @ (Wa@We)^T + (Wa@b_embed + b_attr).

// Pre-fragmented B layout (verified R4-R7): frag f = ks*4+n is a 1KB block at
// half-index f*512; lane L, elem j holds Wc[n*16 + (L&15)][ks*32 + (L>>4)*8 + j].
__device__ __forceinline__ size_t fragidx(int a, int d) {
    return (size_t)(d >> 5) * 2048 + (size_t)(a >> 4) * 512
         + (size_t)((a & 15) | (((d >> 3) & 3) << 4)) * 8 + (d & 7);
}

// ================= prep: fragmented W_comb + b_comb + counter zero ===========
// Separate launch so wfrag/bc cross a kernel boundary (runtime coherence).
__global__ __launch_bounds__(256) void prep_kernel(
    const float* __restrict__ We, const float* __restrict__ be,
    const float* __restrict__ Wa, const float* __restrict__ ba,
    _Float16* __restrict__ wfrag, float* __restrict__ bc,
    unsigned int* __restrict__ counter)
{
    const int wave = threadIdx.x >> 6;
    const int lane = threadIdx.x & 63;
    const int Wu = __builtin_amdgcn_readfirstlane((int)blockIdx.x * 4 + wave);

    if (Wu < 312) {
        // wc[a][d] = sum_k Wa[a][k] * We[k][d]; 2 attrs x 64 cols per wave.
        const int pair = Wu / 12;
        const int dchunk = Wu - pair * 12;
        const int a0 = pair * 2;
        const bool has1 = (a0 + 1 < PA);
        const int d = dchunk * 64 + lane;
        const float* wa0 = Wa + (size_t)a0 * PD;                 // wave-uniform -> s_load
        const float* wa1 = Wa + (size_t)(has1 ? a0 + 1 : a0) * PD;
        float acc0 = 0.f, acc1 = 0.f;
        #pragma unroll 32
        for (int k = 0; k < PD; ++k) {
            float w = We[(size_t)k * PD + d];   // coalesced 256B/wave
            acc0 = fmaf(w, wa0[k], acc0);
            acc1 = fmaf(w, wa1[k], acc1);
        }
        wfrag[fragidx(a0, d)] = (_Float16)acc0;
        if (has1) wfrag[fragidx(a0 + 1, d)] = (_Float16)acc1;
    } else if (Wu < 325) {
        // zero pad rows 51..63 so B reads defined data
        const int r = PA + (Wu - 312);
        #pragma unroll
        for (int j = 0; j < 12; ++j)
            wfrag[fragidx(r, j * 64 + lane)] = (_Float16)0.f;
    } else if (Wu < 376) {
        // bc[a] = dot(Wa[a], b_embed) + b_attr[a]; one wave per attr
        const int a = Wu - 325;
        float p = 0.f;
        #pragma unroll
        for (int j = 0; j < 12; ++j) {
            int k = j * 64 + lane;
            p = fmaf(Wa[(size_t)a * PD + k], be[k], p);
        }
        #pragma unroll
        for (int off = 32; off; off >>= 1) p += __shfl_down(p, off);
        if (lane == 0) bc[a] = p + ba[a];
    } else if (Wu == 376) {
        if (lane == 0) *counter = 0u;            // reset last-block counter each replay
    }
}

// ================= GEMM: LDS-free, asm-free, high-occupancy ==================
// 1024 blocks x 256 thr; block = 16 rows; 4 waves K-split (192 each).
// 4 blocks/CU = 16 waves/CU (vs 4 in R5-R7). A-frags: two plain float4 loads
// per lane straight from X (each element read exactly once). B-frags: direct
// coalesced 1KB wave loads from pre-fragmented wfrag (L2-resident, shared by
// all blocks). No LDS staging, no global_load_lds, no inline asm, no barriers
// in the loop -- compiler schedules its own waitcnts.
__global__ void __launch_bounds__(256, 4) gemm_kernel(
    const float* __restrict__ X,        // [16384][768] fp32
    const _Float16* __restrict__ Wfrag, // 96KB pre-fragmented
    const float* __restrict__ bc,       // [64]
    const float* __restrict__ gamma,
    const float* __restrict__ beta,
    float* __restrict__ logits,         // [16384][51] ws
    unsigned long long* __restrict__ part,  // [1024][64] packed {sum,ssq}
    unsigned int* __restrict__ counter,
    float* __restrict__ ss)             // [0..63]=scale, [64..127]=shift
{
    __shared__ float s_out[16][64];     // combined C tile
    __shared__ float s_sum[64];
    __shared__ float s_ssq[64];
    __shared__ float redS[256];
    __shared__ float redQ[256];
    __shared__ int s_last;

    const int tid = threadIdx.x;
    const int wave = tid >> 6;          // k-quarter 0..3
    const int lane = tid & 63;
    const int quad = lane >> 4;
    const int l16 = lane & 15;
    const int b = (int)blockIdx.x;

    #pragma unroll
    for (int i = 0; i < 4; ++i) ((float*)s_out)[i * 256 + tid] = 0.f;
    if (tid < 64) { s_sum[tid] = 0.f; s_ssq[tid] = 0.f; }
    __syncthreads();

    floatx4 acc[4];
    #pragma unroll
    for (int n = 0; n < 4; ++n) acc[n] = (floatx4){0.f, 0.f, 0.f, 0.f};

    // my A source: row = b*16 + l16 (verified frag layout: m=l16, k=quad*8+j)
    const float* xrow = X + (size_t)(b * 16 + l16) * PD + wave * 192 + quad * 8;
    // my B source: frags ks=wave*6+s (global k-step), 16B/lane coalesced
    const _Float16* bbase = Wfrag + (size_t)(wave * 6) * 2048 + (size_t)lane * 8;

    #pragma unroll
    for (int s = 0; s < 6; ++s) {
        floatx4 p0 = *(const floatx4*)(xrow + s * 32);
        floatx4 p1 = *(const floatx4*)(xrow + s * 32 + 4);
        halfx8 af;
        af[0] = (_Float16)p0[0]; af[1] = (_Float16)p0[1];
        af[2] = (_Float16)p0[2]; af[3] = (_Float16)p0[3];
        af[4] = (_Float16)p1[0]; af[5] = (_Float16)p1[1];
        af[6] = (_Float16)p1[2]; af[7] = (_Float16)p1[3];
        #pragma unroll
        for (int n = 0; n < 4; ++n) {
            halfx8 bf = *(const halfx8*)(bbase + (size_t)(s * 4 + n) * 512);
            acc[n] = __builtin_amdgcn_mfma_f32_16x16x32_f16(af, bf, acc[n], 0, 0, 0);
        }
    }

    // combine K-split partials across the 4 waves (LDS float atomics, 4-way)
    // D layout (verified): col = n*16 + l16, row = quad*4 + r
    #pragma unroll
    for (int n = 0; n < 4; ++n)
        #pragma unroll
        for (int r = 0; r < 4; ++r)
            atomicAdd(&s_out[quad * 4 + r][n * 16 + l16], acc[n][r]);
    __syncthreads();

    // bias + logits write + block partial stats
    {
        const int col = tid & 63;
        const int rg = tid >> 6;            // row group 0..3
        if (col < PA) {
            float bv = bc[col];
            float ps = 0.f, pss = 0.f;
            #pragma unroll
            for (int r = 0; r < 4; ++r) {
                float v = s_out[rg * 4 + r][col] + bv;
                logits[(size_t)(b * 16 + rg * 4 + r) * PA + col] = v;
                ps += v; pss += v * v;
            }
            atomicAdd(&s_sum[col], ps);
            atomicAdd(&s_ssq[col], pss);
        }
    }
    __syncthreads();

    // publish per-block partials: 64 packed 8-B atomic stores, distinct addrs
    if (tid < 64) {
        union { floatx2 f; unsigned long long u; } v;
        v.f = (floatx2){s_sum[tid], s_ssq[tid]};
        __hip_atomic_store(&part[(size_t)b * 64 + tid], v.u,
                           __ATOMIC_RELAXED, __HIP_MEMORY_SCOPE_AGENT);
    }
    __syncthreads();   // partial store + logits issued before arrival

    // last-block pattern: only the final arriver reduces; nobody waits
    if (tid == 0) {
        unsigned int old = __hip_atomic_fetch_add(counter, 1u, __ATOMIC_ACQ_REL,
                                                  __HIP_MEMORY_SCOPE_AGENT);
        s_last = (old == NBLK - 1u);
    }
    __syncthreads();
    if (s_last) {
        // reduce 1024x64 partials: thread (q=tid>>6, col=tid&63) sums quarter q
        const int col = tid & 63;
        const int q = tid >> 6;
        float rs = 0.f, rq = 0.f;
        #pragma unroll 8
        for (int i = q * 256; i < q * 256 + 256; ++i) {  // coalesced 512B/wave
            union { unsigned long long u; floatx2 f; } v;
            v.u = __hip_atomic_load(&part[(size_t)i * 64 + col],
                                    __ATOMIC_RELAXED, __HIP_MEMORY_SCOPE_AGENT);
            rs += v.f[0]; rq += v.f[1];
        }
        redS[tid] = rs; redQ[tid] = rq;
        __syncthreads();
        const float invB = 1.0f / (float)PM;
        if (tid < PA) {
            float s  = redS[tid] + redS[64 + tid] + redS[128 + tid] + redS[192 + tid];
            float sq = redQ[tid] + redQ[64 + tid] + redQ[128 + tid] + redQ[192 + tid];
            float mean = s * invB;
            float var  = sq * invB - mean * mean;
            float inv  = rsqrtf(var + 1e-5f);
            float sc = gamma[tid] * inv;
            ss[tid] = sc;
            ss[64 + tid] = beta[tid] - mean * sc;   // kernel boundary publishes
        }
    }
}

// ================= BN finalize: logits * scale + shift -> out ================
// 816 blocks x 256 thr, one float4 per thread (208896 float4s exactly).
__global__ __launch_bounds__(256) void bn_kernel(
    const float* __restrict__ logits,
    const float* __restrict__ ss,       // [0..63]=scale, [64..127]=shift
    float* __restrict__ out)
{
    __shared__ float sc[64];
    __shared__ float sh[64];
    const int t = threadIdx.x;
    if (t < 64) { sc[t] = ss[t]; sh[t] = ss[64 + t]; }
    __syncthreads();

    const int idx = (int)blockIdx.x * 256 + t;      // float4 index
    floatx4 v = ((const floatx4*)logits)[idx];
    int c0 = (idx * 4) % 51;                        // compiler magic-mul
    int c1 = c0 + 1; if (c1 >= 51) c1 -= 51;
    int c2 = c1 + 1; if (c2 >= 51) c2 -= 51;
    int c3 = c2 + 1; if (c3 >= 51) c3 -= 51;
    floatx4 r;
    r[0] = v[0] * sc[c0] + sh[c0];
    r[1] = v[1] * sc[c1] + sh[c1];
    r[2] = v[2] * sc[c2] + sh[c2];
    r[3] = v[3] * sc[c3] + sh[c3];
    ((floatx4*)out)[idx] = r;
}

// ------------------- launch -------------------
extern "C" void kernel_launch(void* const* d_in, const int* in_sizes, int n_in,
                              void* d_out, int out_size, void* d_ws, size_t ws_size,
                              hipStream_t stream) {
    const float* x       = (const float*)d_in[0];
    const float* W_embed = (const float*)d_in[1];
    const float* b_embed = (const float*)d_in[2];
    const float* W_attr  = (const float*)d_in[3];
    const float* b_attr  = (const float*)d_in[4];
    const float* gamma   = (const float*)d_in[5];
    const float* beta    = (const float*)d_in[6];
    float* out = (float*)d_out;

    char* ws = (char*)d_ws;
    _Float16* wfrag       = (_Float16*)(ws);              // 98304 B
    float* bc             = (float*)(ws + 98304);         // 256 B
    unsigned int* counter = (unsigned int*)(ws + 98560);  // 4 B (padded)
    unsigned long long* part = (unsigned long long*)(ws + 98816); // 1024*64*8 = 524288 B
    float* ssbuf          = (float*)(ws + 623104);        // 512 B
    float* logits         = (float*)(ws + 623616);        // 3342336 B

    prep_kernel<<<95, 256, 0, stream>>>(W_embed, b_embed, W_attr, b_attr,
                                        wfrag, bc, counter);
    gemm_kernel<<<1024, 256, 0, stream>>>(x, wfrag, bc, gamma, beta,
                                          logits, part, counter, ssbuf);
    bn_kernel<<<816, 256, 0, stream>>>(logits, ssbuf, out);
}